// Round 6
// baseline (25.287 us; speedup 1.0000x reference)
//
#include <hip/hip_runtime.h>
#include <math.h>

#define NP 196
#define NCLS 10

// Block = 256 threads (4 waves), one image per block, grid = B = 1024.
//  Phase 1 : t<196: expvals e[t] (float4) via __cosf, inv, sqrt-scaled
//            thresholds (sh,sl)=(sqrt(.8),sqrt(.5))*||e|| -> LDS.
//  Phase 2 : wave w: m in [49w,49w+49); lane<49 owns patches n=lane+49k.
//            Packed-fp32 (v_pk_mul/fma_f32) dot + weighted accumulation:
//            11 VALU/pair vs 13 scalar. Edge test |qn.e_m| >= sh_m / sl_m.
//  Phase 2b: t<196 combines 4 wave-partials, removes self-edge (mirrors the
//            pk pairing order exactly), builds feats float4 -> LDS.
//  Phase 3 : t<160: class j=t>>4, slice s=t&15 dots feat x W, 16-lane reduce.
//  Phase 4 : t<10 computes log_softmax, stores out[b,10].

__device__ __forceinline__ float2 pk_mul(float2 a, float2 b) {
    float2 d;
    asm("v_pk_mul_f32 %0, %1, %2" : "=v"(d) : "v"(a), "v"(b));
    return d;
}
__device__ __forceinline__ float2 pk_fma(float2 a, float2 b, float2 c) {
    float2 d;
    asm("v_pk_fma_f32 %0, %1, %2, %3" : "=v"(d) : "v"(a), "v"(b), "v"(c));
    return d;
}

__global__ __launch_bounds__(256) void quanv_fused_kernel(
    const float* __restrict__ x,    // [B,784]
    const float* __restrict__ phi,  // [B,196,4]
    const float* __restrict__ W,    // [10,784]
    const float* __restrict__ bl,   // [10]
    float* __restrict__ out)        // [B,10]
{
    const int b    = blockIdx.x;
    const int t    = threadIdx.x;
    const int wave = t >> 6;
    const int lane = t & 63;

    __shared__ float4 e_s[NP];      // expvals
    __shared__ float  inv_s[NP];    // 1/(||e||+1e-12)
    __shared__ float2 thr_s[NP];    // (sqrt(0.8)*nm, sqrt(0.5)*nm)
    __shared__ float4 pa_s[4 * NP]; // per-wave partial a
    __shared__ float  pd_s[4 * NP]; // per-wave partial deg
    __shared__ float4 feat_s[NP];
    __shared__ float  logit_s[NCLS];

    const float* xb = x + (size_t)b * 784;
    const float* pb = phi + (size_t)b * 784;

    // ---- Phase 1 ----
    if (t < NP) {
        const int hp = t / 14, wp = t - hp * 14;
        const int r0 = hp * 2, c0 = wp * 2;
        float th0 = xb[r0 * 28 + c0];
        float th1 = xb[r0 * 28 + c0 + 1];
        float th2 = xb[(r0 + 1) * 28 + c0];
        float th3 = xb[(r0 + 1) * 28 + c0 + 1];
        float4 ph = *(const float4*)(pb + t * 4);
        float z0 = __cosf(th0) * __cosf(ph.x);
        float z1 = __cosf(th1) * __cosf(ph.y);
        float z2 = __cosf(th2) * __cosf(ph.z);
        float z3 = __cosf(th3) * __cosf(ph.w);
        float e0 = z0;
        float e1 = e0 * z1;
        float e2 = e1 * z2;
        float e3 = e2 * z3;
        e_s[t] = make_float4(e0, e1, e2, e3);
        float nn = sqrtf(e0 * e0 + e1 * e1 + e2 * e2 + e3 * e3) + 1e-12f;
        inv_s[t] = 1.0f / nn;
        thr_s[t] = make_float2(0.8944271909999159f * nn,   // sqrt(0.8)*nm
                               0.7071067811865476f * nn);  // sqrt(0.5)*nm
    }
    __syncthreads();

    // ---- Phase 2 ----
    if (lane < 49) {
        float2 qA[4], qB[4];        // normalized (x,y) and (z,w)
        float2 aA[4], aB[4];        // accumulators
        float  deg[4];
        #pragma unroll
        for (int k = 0; k < 4; ++k) {
            const int n = lane + 49 * k;
            float4 q = e_s[n];
            float iv = inv_s[n];
            qA[k] = make_float2(q.x * iv, q.y * iv);
            qB[k] = make_float2(q.z * iv, q.w * iv);
            aA[k] = make_float2(0.f, 0.f);
            aB[k] = make_float2(0.f, 0.f);
            deg[k] = 0.f;
        }
        const int m0 = wave * 49;
        #pragma unroll 4
        for (int m = m0; m < m0 + 49; ++m) {
            float4 em = e_s[m];      // wave-uniform broadcast
            float2 th = thr_s[m];
            float2 emA = make_float2(em.x, em.y);
            float2 emB = make_float2(em.z, em.w);
            #pragma unroll
            for (int k = 0; k < 4; ++k) {
                float2 t2 = pk_mul(qA[k], emA);     // (qx*ex, qy*ey)
                t2 = pk_fma(qB[k], emB, t2);        // (+qz*ez, +qw*ew)
                float d  = t2.x + t2.y;
                float ad = fabsf(d);
                float w  = (ad >= th.x) ? 1.0f : ((ad >= th.y) ? 0.5f : 0.0f);
                deg[k] += w;
                float2 w2 = make_float2(w, w);
                aA[k] = pk_fma(w2, emA, aA[k]);
                aB[k] = pk_fma(w2, emB, aB[k]);
            }
        }
        #pragma unroll
        for (int k = 0; k < 4; ++k) {
            pa_s[wave * NP + lane + 49 * k] =
                make_float4(aA[k].x, aA[k].y, aB[k].x, aB[k].y);
            pd_s[wave * NP + lane + 49 * k] = deg[k];
        }
    }
    __syncthreads();

    // ---- Phase 2b: combine partials, self-subtract, build feats ----
    if (t < NP) {
        float4 e  = e_s[t];
        float  iv = inv_s[t];
        float2 th = thr_s[t];
        float4 at = make_float4(0.f, 0.f, 0.f, 0.f);
        float  dt = 0.f;
        #pragma unroll
        for (int w = 0; w < 4; ++w) {
            float4 p = pa_s[w * NP + t];
            at.x += p.x; at.y += p.y; at.z += p.z; at.w += p.w;
            dt += pd_s[w * NP + t];
        }
        // self-edge: mirror the packed pairing order exactly:
        // lo = fma(qz, ez, qx*ex); hi = fma(qw, ew, qy*ey); d = lo + hi
        float qx = e.x * iv, qy = e.y * iv, qz = e.z * iv, qw = e.w * iv;
        float lo = __builtin_fmaf(qz, e.z, qx * e.x);
        float hi = __builtin_fmaf(qw, e.w, qy * e.y);
        float d  = lo + hi;
        float ad = fabsf(d);
        float w  = (ad >= th.x) ? 1.0f : ((ad >= th.y) ? 0.5f : 0.0f);
        dt -= w;
        at.x -= w * e.x; at.y -= w * e.y; at.z -= w * e.z; at.w -= w * e.w;
        const float s = 1.0f + dt;   // smooth = I + D - W
        feat_s[t] = make_float4(s * e.x - at.x, s * e.y - at.y,
                                s * e.z - at.z, s * e.w - at.w);
    }
    __syncthreads();

    // ---- Phase 3: logits ----
    if (t < NCLS * 16) {
        const int j  = t >> 4;
        const int sl = t & 15;
        const float4* wr = (const float4*)(W + j * 784);
        float p = 0.f;
        for (int i = sl; i < NP; i += 16) {
            float4 f  = feat_s[i];
            float4 w4 = wr[i];
            p += f.x * w4.x + f.y * w4.y + f.z * w4.z + f.w * w4.w;
        }
        #pragma unroll
        for (int off = 8; off > 0; off >>= 1)
            p += __shfl_down(p, off, 16);
        if (sl == 0) logit_s[j] = p + bl[j];
    }
    __syncthreads();

    // ---- Phase 4: log_softmax ----
    if (t < NCLS) {
        float mx = -INFINITY;
        #pragma unroll
        for (int j = 0; j < NCLS; ++j) mx = fmaxf(mx, logit_s[j]);
        float sum = 0.f;
        #pragma unroll
        for (int j = 0; j < NCLS; ++j) sum += expf(logit_s[j] - mx);
        out[(size_t)b * NCLS + t] = logit_s[t] - mx - logf(sum);
    }
}

extern "C" void kernel_launch(void* const* d_in, const int* in_sizes, int n_in,
                              void* d_out, int out_size, void* d_ws, size_t ws_size,
                              hipStream_t stream) {
    const float* x   = (const float*)d_in[0];   // [B,1,28,28]
    const float* phi = (const float*)d_in[1];   // [B,196,4]
    const float* W   = (const float*)d_in[2];   // [10,784]
    const float* bl  = (const float*)d_in[3];   // [10]
    float* out = (float*)d_out;                 // [B,10]

    const int B = in_sizes[0] / 784;
    quanv_fused_kernel<<<dim3(B), dim3(256), 0, stream>>>(x, phi, W, bl, out);
}

// Round 7
// 22.476 us; speedup vs baseline: 1.1251x; 1.1251x over previous
//
#include <hip/hip_runtime.h>
#include <math.h>

#define NP 196
#define NCLS 10

// Block = 256 threads (4 waves), one image per block, grid = B = 1024.
//  Phase 1 : t<196: expvals e[t] (float4) via __cosf, inv, sqrt-scaled
//            thresholds (sh,sl)=(sqrt(.8),sqrt(.5))*||e|| -> LDS.
//  Phase 2 : wave w: m in [49w,49w+49). FULL 64-lane utilization:
//            each lane owns 3 patches n=lane+64k (0..191); the 4 leftover
//            patches (192..195) are a tail where lane=(patch=lane&3,
//            slice=lane>>2) strides the wave's m-range by 16, then a
//            shfl_xor butterfly (4,8,16,32 — preserves lane&3) reduces.
//            Edge test |qn.e_m| >= sh_m / sl_m (no d^2, no inv^2 in loop).
//  Phase 2b: t<196 combines 4 wave-partials, removes self-edge (identical
//            C dot expression -> identical codegen -> same w), feats -> LDS.
//  Phase 3 : t<160: class j=t>>4, slice s=t&15 dots feat x W, 16-lane reduce.
//  Phase 4 : t<10 computes log_softmax, stores out[b,10].
__global__ __launch_bounds__(256, 4) void quanv_fused_kernel(
    const float* __restrict__ x,    // [B,784]
    const float* __restrict__ phi,  // [B,196,4]
    const float* __restrict__ W,    // [10,784]
    const float* __restrict__ bl,   // [10]
    float* __restrict__ out)        // [B,10]
{
    const int b    = blockIdx.x;
    const int t    = threadIdx.x;
    const int wave = t >> 6;
    const int lane = t & 63;

    __shared__ float4 e_s[NP];      // expvals
    __shared__ float  inv_s[NP];    // 1/(||e||+1e-12)
    __shared__ float2 thr_s[NP];    // (sqrt(0.8)*nm, sqrt(0.5)*nm)
    __shared__ float4 pa_s[4 * NP]; // per-wave partial a
    __shared__ float  pd_s[4 * NP]; // per-wave partial deg
    __shared__ float4 feat_s[NP];
    __shared__ float  logit_s[NCLS];

    const float* xb = x + (size_t)b * 784;
    const float* pb = phi + (size_t)b * 784;

    // ---- Phase 1 ----
    if (t < NP) {
        const int hp = t / 14, wp = t - hp * 14;
        const int r0 = hp * 2, c0 = wp * 2;
        float th0 = xb[r0 * 28 + c0];
        float th1 = xb[r0 * 28 + c0 + 1];
        float th2 = xb[(r0 + 1) * 28 + c0];
        float th3 = xb[(r0 + 1) * 28 + c0 + 1];
        float4 ph = *(const float4*)(pb + t * 4);
        float z0 = __cosf(th0) * __cosf(ph.x);
        float z1 = __cosf(th1) * __cosf(ph.y);
        float z2 = __cosf(th2) * __cosf(ph.z);
        float z3 = __cosf(th3) * __cosf(ph.w);
        float e0 = z0;
        float e1 = e0 * z1;
        float e2 = e1 * z2;
        float e3 = e2 * z3;
        e_s[t] = make_float4(e0, e1, e2, e3);
        float nn = sqrtf(e0 * e0 + e1 * e1 + e2 * e2 + e3 * e3) + 1e-12f;
        inv_s[t] = 1.0f / nn;
        thr_s[t] = make_float2(0.8944271909999159f * nn,   // sqrt(0.8)*nm
                               0.7071067811865476f * nn);  // sqrt(0.5)*nm
    }
    __syncthreads();

    // ---- Phase 2: main (all 64 lanes, 3 patches each) ----
    float4 qn[3];
    float4 a[3];
    float  deg[3];
    #pragma unroll
    for (int k = 0; k < 3; ++k) {
        const int n = lane + 64 * k;
        float4 q = e_s[n];
        float iv = inv_s[n];
        qn[k] = make_float4(q.x * iv, q.y * iv, q.z * iv, q.w * iv);
        a[k] = make_float4(0.f, 0.f, 0.f, 0.f);
        deg[k] = 0.f;
    }
    const int m0 = wave * 49;
    #pragma unroll 7
    for (int m = m0; m < m0 + 49; ++m) {
        float4 em = e_s[m];      // wave-uniform broadcast
        float2 th = thr_s[m];
        #pragma unroll
        for (int k = 0; k < 3; ++k) {
            float d  = qn[k].x * em.x + qn[k].y * em.y + qn[k].z * em.z + qn[k].w * em.w;
            float ad = fabsf(d);
            float w  = (ad >= th.x) ? 1.0f : ((ad >= th.y) ? 0.5f : 0.0f);
            deg[k] += w;
            a[k].x += w * em.x;
            a[k].y += w * em.y;
            a[k].z += w * em.z;
            a[k].w += w * em.w;
        }
    }
    #pragma unroll
    for (int k = 0; k < 3; ++k) {
        pa_s[wave * NP + lane + 64 * k] = a[k];
        pd_s[wave * NP + lane + 64 * k] = deg[k];
    }

    // ---- Phase 2 tail: patches 192..195, m-sliced across 16 lane-groups ----
    {
        const int nt    = 192 + (lane & 3);
        const int slice = lane >> 2;
        float4 q = e_s[nt];
        float iv = inv_s[nt];
        float4 qt = make_float4(q.x * iv, q.y * iv, q.z * iv, q.w * iv);
        float4 at = make_float4(0.f, 0.f, 0.f, 0.f);
        float  dt = 0.f;
        for (int m = m0 + slice; m < m0 + 49; m += 16) {
            float4 em = e_s[m];
            float2 th = thr_s[m];
            float d  = qt.x * em.x + qt.y * em.y + qt.z * em.z + qt.w * em.w;
            float ad = fabsf(d);
            float w  = (ad >= th.x) ? 1.0f : ((ad >= th.y) ? 0.5f : 0.0f);
            dt += w;
            at.x += w * em.x;
            at.y += w * em.y;
            at.z += w * em.z;
            at.w += w * em.w;
        }
        // butterfly over slices (offsets preserve lane&3)
        #pragma unroll
        for (int off = 4; off <= 32; off <<= 1) {
            at.x += __shfl_xor(at.x, off, 64);
            at.y += __shfl_xor(at.y, off, 64);
            at.z += __shfl_xor(at.z, off, 64);
            at.w += __shfl_xor(at.w, off, 64);
            dt   += __shfl_xor(dt,   off, 64);
        }
        if (lane < 4) {
            pa_s[wave * NP + 192 + lane] = at;
            pd_s[wave * NP + 192 + lane] = dt;
        }
    }
    __syncthreads();

    // ---- Phase 2b: combine partials, self-subtract, build feats ----
    if (t < NP) {
        float4 e  = e_s[t];
        float  iv = inv_s[t];
        float2 th = thr_s[t];
        float4 at = make_float4(0.f, 0.f, 0.f, 0.f);
        float  dt = 0.f;
        #pragma unroll
        for (int w = 0; w < 4; ++w) {
            float4 p = pa_s[w * NP + t];
            at.x += p.x; at.y += p.y; at.z += p.z; at.w += p.w;
            dt += pd_s[w * NP + t];
        }
        // self-edge: identical C expression as the loop body -> same w
        float qx = e.x * iv, qy = e.y * iv, qz = e.z * iv, qw = e.w * iv;
        float d  = qx * e.x + qy * e.y + qz * e.z + qw * e.w;
        float ad = fabsf(d);
        float w  = (ad >= th.x) ? 1.0f : ((ad >= th.y) ? 0.5f : 0.0f);
        dt -= w;
        at.x -= w * e.x; at.y -= w * e.y; at.z -= w * e.z; at.w -= w * e.w;
        const float s = 1.0f + dt;   // smooth = I + D - W
        feat_s[t] = make_float4(s * e.x - at.x, s * e.y - at.y,
                                s * e.z - at.z, s * e.w - at.w);
    }
    __syncthreads();

    // ---- Phase 3: logits ----
    if (t < NCLS * 16) {
        const int j  = t >> 4;
        const int sl = t & 15;
        const float4* wr = (const float4*)(W + j * 784);
        float p = 0.f;
        for (int i = sl; i < NP; i += 16) {
            float4 f  = feat_s[i];
            float4 w4 = wr[i];
            p += f.x * w4.x + f.y * w4.y + f.z * w4.z + f.w * w4.w;
        }
        #pragma unroll
        for (int off = 8; off > 0; off >>= 1)
            p += __shfl_down(p, off, 16);
        if (sl == 0) logit_s[j] = p + bl[j];
    }
    __syncthreads();

    // ---- Phase 4: log_softmax ----
    if (t < NCLS) {
        float mx = -INFINITY;
        #pragma unroll
        for (int j = 0; j < NCLS; ++j) mx = fmaxf(mx, logit_s[j]);
        float sum = 0.f;
        #pragma unroll
        for (int j = 0; j < NCLS; ++j) sum += expf(logit_s[j] - mx);
        out[(size_t)b * NCLS + t] = logit_s[t] - mx - logf(sum);
    }
}

extern "C" void kernel_launch(void* const* d_in, const int* in_sizes, int n_in,
                              void* d_out, int out_size, void* d_ws, size_t ws_size,
                              hipStream_t stream) {
    const float* x   = (const float*)d_in[0];   // [B,1,28,28]
    const float* phi = (const float*)d_in[1];   // [B,196,4]
    const float* W   = (const float*)d_in[2];   // [10,784]
    const float* bl  = (const float*)d_in[3];   // [10]
    float* out = (float*)d_out;                 // [B,10]

    const int B = in_sizes[0] / 784;
    quanv_fused_kernel<<<dim3(B), dim3(256), 0, stream>>>(x, phi, W, bl, out);
}